// Round 5
// baseline (161.859 us; speedup 1.0000x reference)
//
#include <hip/hip_runtime.h>
#include <hip/hip_bf16.h>

typedef __bf16 bf16;
typedef __bf16 bf16x4 __attribute__((ext_vector_type(4)));
typedef __bf16 bf16x8 __attribute__((ext_vector_type(8)));
typedef float f32x4 __attribute__((ext_vector_type(4)));

#define DIM 768
#define HW 1024          // 32*32
#define BATCH 16
#define M_TOTAL (BATCH * HW)   // 16384
#define NKT 12                 // K-tiles of 64

#define AS1 __attribute__((address_space(1)))
#define AS3 __attribute__((address_space(3)))

// ======================== k-permutation convention =========================
// All bf16 [.][768] activation buffers and Wb[768][768] store the k (channel)
// dimension permuted within each 32-group: physical position p = 8g+j holds
// logical k = 4g+j (j<4) or 4g+8+j (j>=4, i.e. k=16+4g+(j-4)).  This makes the
// mfma_f32_16x16x32_bf16 fragment (lane: k in {4q..4q+3} u {16+4q..16+4q+3},
// q=lane>>4) CONTIGUOUS 16B in LDS -> single ds_read_b128 per fragment.
// k2pos(kk) = (((kk&15)>>2)<<3) + (kk&3) + ((kk>>4)<<2).

// ---------------- weight convert: f32 -> bf16, k-permuted ----------------
__global__ void wcvt3_kernel(const float4* __restrict__ w1, const float4* __restrict__ w2,
                             const float4* __restrict__ w3,
                             bf16x8* __restrict__ o1, bf16x8* __restrict__ o2,
                             bf16x8* __restrict__ o3) {
    const int b = blockIdx.x;              // 0..863
    const int which = b / 288;
    const int i = (b % 288) * 256 + threadIdx.x;   // 0..73727 output 16B blocks
    const float4* w = which == 0 ? w1 : which == 1 ? w2 : w3;
    bf16x8* o = which == 0 ? o1 : which == 1 ? o2 : o3;
    const int row = i / 96, br = i % 96;   // 96 blocks per 768-row
    const int q = br >> 2, g = br & 3;     // 32-group, block-in-group
    float4 lo = w[row * 192 + q * 8 + g];        // k = 32q + 4g .. +3
    float4 hi = w[row * 192 + q * 8 + g + 4];    // k = 32q + 16 + 4g .. +3
    bf16x8 r = { (bf16)lo.x, (bf16)lo.y, (bf16)lo.z, (bf16)lo.w,
                 (bf16)hi.x, (bf16)hi.y, (bf16)hi.z, (bf16)hi.w };
    o[row * 96 + br] = r;
}

// ------- transpose + convert: x[16][768][1024] f32 -> xb[16384][768p] bf16 -------
__global__ void transpose_cvt_kernel(const float* __restrict__ x, bf16* __restrict__ xb) {
    __shared__ float tile[32][33];
    const int b = blockIdx.z;
    const int hw0 = blockIdx.x * 32;
    const int c0 = blockIdx.y * 32;
    const int tx = threadIdx.x, ty = threadIdx.y;  // 32 x 8

    const float* src = x + ((size_t)b * DIM + c0) * HW + hw0;
#pragma unroll
    for (int j = 0; j < 4; j++)
        tile[ty + 8 * j][tx] = src[(size_t)(ty + 8 * j) * HW + tx];
    __syncthreads();
    // k2pos(tx) within the 32-group
    const int ptx = (((tx & 15) >> 2) << 3) + (tx & 3) + ((tx >> 4) << 2);
    bf16* dst = xb + ((size_t)b * HW + hw0) * DIM + c0;
#pragma unroll
    for (int j = 0; j < 4; j++)
        dst[(size_t)(ty + 8 * j) * DIM + ptx] = (bf16)tile[tx][ty + 8 * j];
}

// ---------------- GEMM: 256x192 tile, BK=64, 8 waves (4x2), 8-phase ----------------
// grid = (16384/256) * (768/192) = 64*4 = 256 blocks = exactly 1/CU.
// Staging: 7 chunks/K-tile (A0..A3, B0..B2; 64 rows = 8KB = 1 global_load_lds
// per thread). P0: kt+1 A2,A3; P1: kt+1 B0,B1; P2: kt+1 B2; P3: kt+2 A0,A1
// + counted vmcnt(2) (kt+1 resident, kt+2 chunks stay in flight).
// LDS 16B-block XOR swizzle (blk ^= row&7): linear LDS dest + pre-swizzled
// global source, same XOR on fragment reads (both-sides-or-neither).
// MODE 0: write bf16 [n][768] k-permuted (+bias). MODE 1: write f32 NCHW (+bias).
template <int MODE>
__global__ __launch_bounds__(512, 2) void gemm_kernel(
    const bf16* __restrict__ A,   // [M][768] k-permuted
    const bf16* __restrict__ Bw,  // [768][768] rows linear, cols k-permuted
    const float* __restrict__ bias,
    void* __restrict__ out)
{
    constexpr int K = DIM;
    __shared__ bf16 ldsA[2][256][64];   // 64 KiB
    __shared__ bf16 ldsB[2][192][64];   // 48 KiB

    const int t = threadIdx.x;
    const int lane = t & 63;
    const int wave = t >> 6;
    const int wm = wave >> 1, wn = wave & 1;   // 4 x 2 waves -> wave tile 64x96

    const int bid = blockIdx.x;                 // 256 blocks, bijective XCD swizzle
    const int swz = (bid & 7) * 32 + (bid >> 3);
    const int m0 = (swz & 63) << 8;             // 64 m-tiles of 256
    const int n0 = (swz >> 6) * 192;            // 4 n-tiles of 192

    const int fr = lane & 15;
    const int fq = lane >> 4;

    f32x4 acc[4][6] = {};

    const int s_r = t >> 3;     // 0..63, staging row within chunk
    const int s_blk = t & 7;    // staging 16B block in row

    auto stage_chunk = [&](int kt, int which, int chunk) {
        const int d = kt & 1;
        const int r = chunk * 64 + s_r;
        if (which == 0)
            __builtin_amdgcn_global_load_lds(
                (const AS1 void*)(A + (size_t)(m0 + r) * K + kt * 64 + ((s_blk ^ (r & 7)) << 3)),
                (AS3 void*)&ldsA[d][r][s_blk * 8], 16, 0, 0);
        else
            __builtin_amdgcn_global_load_lds(
                (const AS1 void*)(Bw + (size_t)(n0 + r) * K + kt * 64 + ((s_blk ^ (r & 7)) << 3)),
                (AS3 void*)&ldsB[d][r][s_blk * 8], 16, 0, 0);
    };

    bf16x8 a[4], b0[6], b1[6];

    auto ldA = [&](int kt, int mh) {   // 4 x ds_read_b128
        const int d = kt & 1;
#pragma unroll
        for (int mi = 0; mi < 2; mi++) {
            const int R = wm * 64 + (mh * 2 + mi) * 16 + fr;
            const bf16* rp = &ldsA[d][R][0];
            const int s = R & 7;
#pragma unroll
            for (int ks = 0; ks < 2; ks++)
                a[mi * 2 + ks] = *(const bf16x8*)(rp + (((ks * 4 + fq) ^ s) << 3));
        }
    };
    auto ldB = [&](bf16x8* bb, int kt, int nh) {   // 6 x ds_read_b128
        const int d = kt & 1;
#pragma unroll
        for (int ni = 0; ni < 3; ni++) {
            const int R = wn * 96 + (nh * 3 + ni) * 16 + fr;
            const bf16* rp = &ldsB[d][R][0];
            const int s = R & 7;
#pragma unroll
            for (int ks = 0; ks < 2; ks++)
                bb[ni * 2 + ks] = *(const bf16x8*)(rp + (((ks * 4 + fq) ^ s) << 3));
        }
    };
    auto MM = [&](bf16x8* bb, int mh, int nh) {    // 12 MFMA, setprio-wrapped (T5)
        __builtin_amdgcn_s_setprio(1);
#pragma unroll
        for (int mi = 0; mi < 2; mi++)
#pragma unroll
            for (int ni = 0; ni < 3; ni++)
#pragma unroll
                for (int ks = 0; ks < 2; ks++)
                    acc[mh * 2 + mi][nh * 3 + ni] = __builtin_amdgcn_mfma_f32_16x16x32_bf16(
                        a[mi * 2 + ks], bb[ni * 2 + ks], acc[mh * 2 + mi][nh * 3 + ni], 0, 0, 0);
        __builtin_amdgcn_s_setprio(0);
    };

    // prologue: kt0 fully (7 chunks) + kt1 A0,A1 -> vmcnt(2): kt0 resident
    stage_chunk(0, 0, 0); stage_chunk(0, 0, 1); stage_chunk(0, 0, 2); stage_chunk(0, 0, 3);
    stage_chunk(0, 1, 0); stage_chunk(0, 1, 1); stage_chunk(0, 1, 2);
    stage_chunk(1, 0, 0); stage_chunk(1, 0, 1);
    asm volatile("s_waitcnt vmcnt(2)" ::: "memory");
    __builtin_amdgcn_s_barrier();

    for (int kt = 0; kt < NKT; ++kt) {
        // P0: quadrant (mh0, nh0); stage kt+1 A2,A3
        ldA(kt, 0);
        ldB(b0, kt, 0);
        if (kt + 1 < NKT) { stage_chunk(kt + 1, 0, 2); stage_chunk(kt + 1, 0, 3); }
        __builtin_amdgcn_s_barrier();
        asm volatile("s_waitcnt lgkmcnt(0)" ::: "memory");
        MM(b0, 0, 0);
        __builtin_amdgcn_s_barrier();
        // P1: (mh0, nh1); stage kt+1 B0,B1
        ldB(b1, kt, 1);
        if (kt + 1 < NKT) { stage_chunk(kt + 1, 1, 0); stage_chunk(kt + 1, 1, 1); }
        __builtin_amdgcn_s_barrier();
        asm volatile("s_waitcnt lgkmcnt(0)" ::: "memory");
        MM(b1, 0, 1);
        __builtin_amdgcn_s_barrier();
        // P2: (mh1, nh1); stage kt+1 B2; last ds_reads of this dbuf
        ldA(kt, 1);
        if (kt + 1 < NKT) stage_chunk(kt + 1, 1, 2);
        __builtin_amdgcn_s_barrier();
        asm volatile("s_waitcnt lgkmcnt(0)" ::: "memory");
        MM(b1, 1, 1);
        __builtin_amdgcn_s_barrier();
        // P3: (mh1, nh0) from registers; stage kt+2 A0,A1 into the dbuf just
        // freed (all its reads completed before P2-end barrier). Counted
        // vmcnt(2): kt+1 fully resident, kt+2's 2 chunks stay in flight.
        if (kt + 2 < NKT) { stage_chunk(kt + 2, 0, 0); stage_chunk(kt + 2, 0, 1); }
        MM(b0, 1, 0);
        if (kt < NKT - 2) { asm volatile("s_waitcnt vmcnt(2)" ::: "memory"); }
        else if (kt == NKT - 2) { asm volatile("s_waitcnt vmcnt(0)" ::: "memory"); }
        __builtin_amdgcn_s_barrier();
    }

    // ---------------- epilogue ----------------
    const int fq4 = fq * 4;
    if (MODE == 0) {
        bf16* o = (bf16*)out;
#pragma unroll
        for (int mi = 0; mi < 4; mi++) {
            const int row = m0 + wm * 64 + mi * 16 + fq4;
#pragma unroll
            for (int ni = 0; ni < 6; ni++) {
                const int col = n0 + wn * 96 + ni * 16 + fr;   // logical channel
                const int pcol = n0 + wn * 96 + ((ni >> 1) << 5)
                               + ((fr >> 2) << 3) + (fr & 3) + ((ni & 1) << 2); // k2pos
                const float bv = bias[col];
#pragma unroll
                for (int r = 0; r < 4; r++)
                    o[(size_t)(row + r) * DIM + pcol] = (bf16)(acc[mi][ni][r] + bv);
            }
        }
    } else {
        float* o = (float*)out;
#pragma unroll
        for (int mi = 0; mi < 4; mi++) {
            const int nb = m0 + wm * 64 + mi * 16 + fq4;
            const int bI = nb >> 10, hw = nb & 1023;
#pragma unroll
            for (int ni = 0; ni < 6; ni++) {
                const int col = n0 + wn * 96 + ni * 16 + fr;
                f32x4 v = acc[mi][ni] + bias[col];
                *(f32x4*)(o + ((size_t)bI * DIM + col) * HW + hw) = v;
            }
        }
    }
}

// ---------------- LayerNorm + exact GELU, in-place on k-permuted bf16 rows ----------------
__global__ __launch_bounds__(256) void ln_gelu_kernel(
    bf16* __restrict__ h, const float* __restrict__ g, const float* __restrict__ beta)
{
    const int wave = threadIdx.x >> 6;
    const int lane = threadIdx.x & 63;
    const int n = blockIdx.x * 4 + wave;
    bf16* row = h + (size_t)n * DIM;

    float v[12];
    float s = 0.f, ss = 0.f;
#pragma unroll
    for (int j = 0; j < 3; j++) {
        bf16x4 x = *(const bf16x4*)(row + j * 256 + lane * 4);
#pragma unroll
        for (int i = 0; i < 4; i++) {
            float f = (float)x[i];
            v[j * 4 + i] = f;
            s += f;
            ss += f * f;
        }
    }
#pragma unroll
    for (int off = 32; off > 0; off >>= 1) {
        s += __shfl_xor(s, off);
        ss += __shfl_xor(ss, off);
    }
    const float mu = s * (1.f / DIM);
    const float var = ss * (1.f / DIM) - mu * mu;
    const float rstd = rsqrtf(var + 1e-6f);

#pragma unroll
    for (int j = 0; j < 3; j++) {
        bf16x4 r;
#pragma unroll
        for (int i = 0; i < 4; i++) {
            const int c = j * 256 + lane * 4 + i;   // physical position
            const int p = (lane * 4 + i) & 31;
            const int kk = ((p >> 3) << 2) + (p & 7) + ((p & 4) ? 12 : 0);  // pos2k
            const int gi = (c & ~31) + kk;          // logical channel for gamma/beta
            float y = (v[j * 4 + i] - mu) * rstd * g[gi] + beta[gi];
            y = 0.5f * y * (1.f + erff(y * 0.70710678118f));
            r[i] = (bf16)y;
        }
        *(bf16x4*)(row + j * 256 + lane * 4) = r;
    }
}

extern "C" void kernel_launch(void* const* d_in, const int* in_sizes, int n_in,
                              void* d_out, int out_size, void* d_ws, size_t ws_size,
                              hipStream_t stream) {
    const float* x   = (const float*)d_in[0];
    const float* W1  = (const float*)d_in[1];
    const float* b1  = (const float*)d_in[2];
    const float* g1  = (const float*)d_in[3];
    const float* be1 = (const float*)d_in[4];
    const float* W2  = (const float*)d_in[5];
    const float* b2  = (const float*)d_in[6];
    const float* g2  = (const float*)d_in[7];
    const float* be2 = (const float*)d_in[8];
    const float* W3  = (const float*)d_in[9];
    const float* b3  = (const float*)d_in[10];
    float* out = (float*)d_out;

    bf16* Wb1  = (bf16*)d_ws;
    bf16* Wb2  = Wb1 + (size_t)DIM * DIM;
    bf16* Wb3  = Wb2 + (size_t)DIM * DIM;
    bf16* buf0 = Wb3 + (size_t)DIM * DIM;          // 16384*768 bf16
    bf16* buf1 = buf0 + (size_t)M_TOTAL * DIM;

    // weights -> bf16 k-permuted (single launch)
    wcvt3_kernel<<<864, 256, 0, stream>>>((const float4*)W1, (const float4*)W2, (const float4*)W3,
                                          (bf16x8*)Wb1, (bf16x8*)Wb2, (bf16x8*)Wb3);

    // x NCHW -> [n][c] bf16 k-permuted
    transpose_cvt_kernel<<<dim3(32, 24, 16), dim3(32, 8), 0, stream>>>(x, buf0);

    const int ggrid = (M_TOTAL / 256) * (DIM / 192);   // 64*4 = 256
    // layer 1
    gemm_kernel<0><<<ggrid, 512, 0, stream>>>(buf0, Wb1, b1, buf1);
    ln_gelu_kernel<<<M_TOTAL / 4, 256, 0, stream>>>(buf1, g1, be1);
    // layer 2
    gemm_kernel<0><<<ggrid, 512, 0, stream>>>(buf1, Wb2, b2, buf0);
    ln_gelu_kernel<<<M_TOTAL / 4, 256, 0, stream>>>(buf0, g2, be2);
    // layer 3 -> NCHW f32 output
    gemm_kernel<1><<<ggrid, 512, 0, stream>>>(buf0, Wb3, b3, out);
}